// Round 5
// baseline (22732.808 us; speedup 1.0000x reference)
//
#include <hip/hip_runtime.h>
#include <hip/hip_fp16.h>

#define B_   256
#define T_   512
#define D_   200
#define H_   320
#define L_   3
#define G3_  960
#define BH_  (B_*H_)
#define BTH_ (B_*T_*H_)

#define GR_   8              // independent groups (batch split), expect one XCD each
#define RPG_  32             // rows (batch) per group
#define CPB_  48             // output cols per block
#define NCG_  20             // col-groups per layer (960/48)
#define SPG_  60             // blocks per group (3 layers * 20)
#define NBLK  (GR_*SPG_)     // 480
#define NTHR  256
#define KIP0  224            // layer-0 input K padded to 32-multiple
#define WSTR  648            // LDS weight row stride in f16 elems

typedef _Float16 half8 __attribute__((ext_vector_type(8)));
typedef float    f32x4 __attribute__((ext_vector_type(4)));

// ---- ws layout (floats) ----
#define OFF_STATE 0
#define SZ_STATE  (L_*BH_)                 // fp32 hidden state
#define OFF_Z     (OFF_STATE + SZ_STATE)
#define SZ_Z      (L_*B_*G3_)
#define OFF_HN    (OFF_Z + SZ_Z)
#define SZ_HN     (L_*B_*H_)
#define OFF_STF   (OFF_HN + SZ_HN)         // f16 hidden state copy
#define SZ_STF_F  ((L_*BH_)/2)
#define OFF_BAR   (OFF_STF + SZ_STF_F)
#define GBAR_STRIDE 320                    // words per group's barrier region
#define BAR_WORDS   (GR_*GBAR_STRIDE)      // cnt@0, epoch@32, det[60]@64

__device__ __forceinline__ float sigmoidf_(float v) {
    return 1.0f / (1.0f + __expf(-v));
}

__device__ __forceinline__ float wredsum(float v) {
#pragma unroll
    for (int m = 32; m > 0; m >>= 1) v += __shfl_xor(v, m, 64);
    return v;
}

__device__ __forceinline__ half8 h8zero() {
    half8 a;
#pragma unroll
    for (int j = 0; j < 8; ++j) a[j] = (_Float16)0.f;
    return a;
}

// ---------------- group barrier, two flavors ----------------
// token must be unique & increasing per barrier (1,2,3,...). Monotonic counter:
// after barrier #token completes, *cnt == token*SPG_ and *ep == token.
//
// fast (all 60 blocks on ONE XCD): workgroup-scope atomics execute in the
// shared per-XCD TCC(L2); vector L1 is write-through and __syncthreads drains
// vmcnt, so all block stores are already L2-visible. Exit does a vL1-only
// buffer_inv (no sc1 -> no L2 invalidate, no wbl2 anywhere).
//
// safe (any placement): agent-scope fences (proven correct rounds 2-4).
__device__ __forceinline__ void group_barrier(unsigned* cnt, unsigned* ep,
                                              int tid, unsigned token, bool fast) {
    __syncthreads();   // drains vmcnt/lgkmcnt for ALL waves, then s_barrier
    if (tid == 0) {
        if (fast) {
            unsigned old = __hip_atomic_fetch_add(cnt, 1u, __ATOMIC_RELAXED,
                                                  __HIP_MEMORY_SCOPE_WORKGROUP);
            if (old != token*(unsigned)SPG_ - 1u) {
                // poll epoch with an RMW (always executes in TCC -> fresh)
                while ((int)(__hip_atomic_fetch_add(ep, 0u, __ATOMIC_RELAXED,
                               __HIP_MEMORY_SCOPE_WORKGROUP) - token) < 0)
                    __builtin_amdgcn_s_sleep(4);
            } else {
                __hip_atomic_fetch_add(ep, 1u, __ATOMIC_RELAXED,
                                       __HIP_MEMORY_SCOPE_WORKGROUP);
            }
            // invalidate vector L1 only, so plain loads re-read fresh L2
            asm volatile("buffer_inv" ::: "memory");
        } else {
            __threadfence();   // release (wbl2)
            unsigned old = __hip_atomic_fetch_add(cnt, 1u, __ATOMIC_RELAXED,
                                                  __HIP_MEMORY_SCOPE_AGENT);
            if (old != token*(unsigned)SPG_ - 1u) {
                while ((int)(__hip_atomic_load(ep, __ATOMIC_RELAXED,
                               __HIP_MEMORY_SCOPE_AGENT) - token) < 0)
                    __builtin_amdgcn_s_sleep(4);
            } else {
                __hip_atomic_fetch_add(ep, 1u, __ATOMIC_RELEASE,
                                       __HIP_MEMORY_SCOPE_AGENT);
            }
            __threadfence();   // acquire (inv)
        }
    }
    __syncthreads();
}

__device__ __forceinline__ void load_weights(int l, int colbase, int tid,
        const float* __restrict__ wih0, const float* __restrict__ wihr,
        const float* __restrict__ whh,  const float* __restrict__ rmean,
        const float* __restrict__ rvar,
        _Float16 (*w)[WSTR], float (*nrm)[KIP0])
{
    for (int e = tid; e < CPB_*WSTR; e += NTHR) ((_Float16*)w)[e] = (_Float16)0.f;
    if (l == 0) for (int e = tid; e < 2*KIP0; e += NTHR) ((float*)nrm)[e] = 0.f;
    __syncthreads();
    const int KI  = (l == 0) ? D_ : H_;
    const int KIP = (l == 0) ? KIP0 : H_;
    for (int e = tid; e < CPB_*KI; e += NTHR) {
        int c = e / KI, k = e - c*KI;
        float v = (l == 0) ? wih0[(size_t)(colbase + c)*D_ + k]
                           : wihr[((size_t)(l-1)*G3_ + colbase + c)*H_ + k];
        w[c][k] = (_Float16)v;
    }
    for (int e = tid; e < CPB_*H_; e += NTHR) {
        int c = e / H_, k = e - c*H_;
        w[c][KIP + k] = (_Float16)whh[((size_t)l*G3_ + colbase + c)*H_ + k];
    }
    if (l == 0) {
        for (int k = tid; k < D_; k += NTHR) {
            nrm[0][k] = rmean[k];
            nrm[1][k] = rsqrtf(rvar[k] + 1e-8f);
        }
    }
    __syncthreads();
}

template<int KTI, bool L0>
__device__ __forceinline__ void phase1_work(int g, int l, int t, int colbase, int tid,
        const float* __restrict__ x, const _Float16* __restrict__ stf,
        const float* __restrict__ bih, const float* __restrict__ bhh,
        float* __restrict__ zbuf, float* __restrict__ hnbuf,
        const _Float16 (*w)[WSTR], const float (*nrm)[KIP0])
{
    const int wid  = tid >> 6;       // 0 or 1 (callers gate wid<2)
    const int lane = tid & 63;
    const int nr   = lane & 15;
    const int grp  = lane >> 4;
    const int mb   = g*RPG_ + wid*16;
    constexpr int KIP = KTI * 32;

    f32x4 accI[3], accH[3];
#pragma unroll
    for (int nt = 0; nt < 3; ++nt) {
#pragma unroll
        for (int r = 0; r < 4; ++r) { accI[nt][r] = 0.f; accH[nt][r] = 0.f; }
    }

    // ---------- input-to-hidden ----------
#pragma unroll
    for (int kt = 0; kt < KTI; ++kt) {
        const int k0 = kt*32 + grp*8;
        half8 a;
        if (L0) {
            if (kt == KTI-1 && grp > 0) {
                a = h8zero();
            } else {
                const float* xr = &x[((size_t)(mb + nr)*T_ + t)*D_ + k0];
                float xv[8];
                *(float4*)&xv[0] = *(const float4*)xr;
                *(float4*)&xv[4] = *(const float4*)(xr + 4);
#pragma unroll
                for (int j = 0; j < 8; ++j) {
                    float nv = (xv[j] - nrm[0][k0+j]) * nrm[1][k0+j];
                    a[j] = (_Float16)fminf(fmaxf(nv, -10.f), 10.f);
                }
            }
        } else {
            a = *(const half8*)&stf[(size_t)(l-1)*BH_ + (size_t)(mb + nr)*H_ + k0];
        }
#pragma unroll
        for (int nt = 0; nt < 3; ++nt) {
            half8 bf = *(const half8*)&w[nt*16 + nr][k0];
            accI[nt] = __builtin_amdgcn_mfma_f32_16x16x32_f16(a, bf, accI[nt], 0, 0, 0);
        }
    }
    // ---------- hidden-to-hidden (K = 320) ----------
#pragma unroll
    for (int kt = 0; kt < 10; ++kt) {
        const int k0 = kt*32 + grp*8;
        half8 a = *(const half8*)&stf[(size_t)l*BH_ + (size_t)(mb + nr)*H_ + k0];
#pragma unroll
        for (int nt = 0; nt < 3; ++nt) {
            half8 bf = *(const half8*)&w[nt*16 + nr][KIP + k0];
            accH[nt] = __builtin_amdgcn_mfma_f32_16x16x32_f16(a, bf, accH[nt], 0, 0, 0);
        }
    }
    // ---------- store pre-activations ----------
#pragma unroll
    for (int nt = 0; nt < 3; ++nt) {
        const int col = colbase + nt*16 + nr;
        const float bi = bih[l*G3_ + col];
        const float bh = bhh[l*G3_ + col];
        const bool ru = (colbase + nt*16) < 2*H_;
#pragma unroll
        for (int r = 0; r < 4; ++r) {
            const int m = mb + grp*4 + r;
            const size_t zi = ((size_t)l*B_ + m)*G3_ + col;
            if (ru) {
                zbuf[zi] = accI[nt][r] + accH[nt][r] + bi + bh;
            } else {
                zbuf[zi] = accI[nt][r] + bi;
                hnbuf[((size_t)l*B_ + m)*H_ + (col - 2*H_)] = accH[nt][r] + bh;
            }
        }
    }
}

__device__ __forceinline__ void phase1_dispatch(int g, int l, int t, int colbase, int tid,
        const float* x, const _Float16* stf, const float* bih, const float* bhh,
        float* zbuf, float* hnbuf, const _Float16 (*w)[WSTR], const float (*nrm)[KIP0])
{
    if ((tid >> 6) >= 2) return;   // 2 waves of 16 rows cover RPG_=32
    if (l == 0) phase1_work<7,  true >(g, l, t, colbase, tid, x, stf, bih, bhh, zbuf, hnbuf, w, nrm);
    else        phase1_work<10, false>(g, l, t, colbase, tid, x, stf, bih, bhh, zbuf, hnbuf, w, nrm);
}

__device__ __forceinline__ void phase2_work(int g, int tau, int wv, int lane,
        const float* __restrict__ lng, const float* __restrict__ lnb,
        float* __restrict__ state, _Float16* __restrict__ stf,
        const float* __restrict__ zbuf, const float* __restrict__ hnbuf,
        float* __restrict__ out)
{
    if (wv >= L_*RPG_) return;            // 96 tasks per group
    const int l2  = wv >> 5;
    const int row = wv & 31;
    const int b2  = g*RPG_ + row;
    const int t2  = tau - l2;
    if (t2 < 0 || t2 >= T_) return;

    const float* zrow  = &zbuf[((size_t)l2*B_ + b2)*G3_];
    const float* hnrow = &hnbuf[((size_t)l2*B_ + b2)*H_];
    float*       hrow  = &state[(size_t)l2*BH_ + (size_t)b2*H_];
    _Float16*    frow  = &stf[(size_t)l2*BH_ + (size_t)b2*H_];

    float zr[5], zu[5], zn[5], hn[5];
#pragma unroll
    for (int i = 0; i < 5; ++i) {
        const int j = lane + i*64;
        zr[i] = zrow[j];
        zu[i] = zrow[320 + j];
        zn[i] = zrow[640 + j];
        hn[i] = hnrow[j];
    }
    const float inv320 = 1.0f/320.0f;
    float s  = zr[0]+zr[1]+zr[2]+zr[3]+zr[4];
    float mu = wredsum(s) * inv320;
    float vs = 0.f;
#pragma unroll
    for (int i = 0; i < 5; ++i) { float d = zr[i]-mu; vs += d*d; }
    float inv = rsqrtf(wredsum(vs)*inv320 + 1e-5f);
    float r[5];
#pragma unroll
    for (int i = 0; i < 5; ++i) {
        const int j = lane + i*64;
        r[i] = sigmoidf_((zr[i]-mu)*inv * lng[(l2*3+0)*H_ + j] + lnb[(l2*3+0)*H_ + j]);
    }
    s  = zu[0]+zu[1]+zu[2]+zu[3]+zu[4];
    mu = wredsum(s) * inv320;
    vs = 0.f;
#pragma unroll
    for (int i = 0; i < 5; ++i) { float d = zu[i]-mu; vs += d*d; }
    inv = rsqrtf(wredsum(vs)*inv320 + 1e-5f);
    float u[5];
#pragma unroll
    for (int i = 0; i < 5; ++i) {
        const int j = lane + i*64;
        u[i] = sigmoidf_((zu[i]-mu)*inv * lng[(l2*3+1)*H_ + j] + lnb[(l2*3+1)*H_ + j]);
    }
    float z2[5];
#pragma unroll
    for (int i = 0; i < 5; ++i) z2[i] = zn[i] + r[i]*hn[i];
    s  = z2[0]+z2[1]+z2[2]+z2[3]+z2[4];
    mu = wredsum(s) * inv320;
    vs = 0.f;
#pragma unroll
    for (int i = 0; i < 5; ++i) { float d = z2[i]-mu; vs += d*d; }
    inv = rsqrtf(wredsum(vs)*inv320 + 1e-5f);
#pragma unroll
    for (int i = 0; i < 5; ++i) {
        const int j = lane + i*64;
        float nv = tanhf((z2[i]-mu)*inv * lng[(l2*3+2)*H_ + j] + lnb[(l2*3+2)*H_ + j]);
        float hp = hrow[j];
        float hv = (1.0f - u[i])*nv + u[i]*hp;
        hrow[j] = hv;
        frow[j] = (_Float16)hv;
        if (l2 == 2)    out[((size_t)b2*T_ + t2)*H_ + j] = hv;
        if (t2 == T_-1) out[(size_t)BTH_ + ((size_t)l2*B_ + b2)*H_ + j] = hv;
    }
}

// ---- init: zero barrier words, copy h0 into fp32 + f16 state ----
__global__ void k_init(const float* __restrict__ h0, float* __restrict__ ws) {
    float*     state = ws + OFF_STATE;
    _Float16*  stf   = (_Float16*)(ws + OFF_STF);
    unsigned*  bar   = (unsigned*)(ws + OFF_BAR);
    int gt = blockIdx.x*blockDim.x + threadIdx.x;
    if (gt < BAR_WORDS) bar[gt] = 0u;
    for (int i = gt; i < L_*BH_; i += gridDim.x*blockDim.x) {
        float v = h0[i];
        state[i] = v;
        stf[i]   = (_Float16)v;
    }
}

// ======================= cooperative persistent kernel =======================
__launch_bounds__(NTHR)
__global__ void gru_coop_kernel(const float* __restrict__ x,
                                const float* __restrict__ h0,
                                const float* __restrict__ rmean,
                                const float* __restrict__ rvar,
                                const float* __restrict__ wih0,
                                const float* __restrict__ wihr,
                                const float* __restrict__ whh,
                                const float* __restrict__ bih,
                                const float* __restrict__ bhh,
                                const float* __restrict__ lng,
                                const float* __restrict__ lnb,
                                float* __restrict__ out,
                                float* __restrict__ ws)
{
    (void)h0;
    float*     state = ws + OFF_STATE;
    float*     zbuf  = ws + OFF_Z;
    float*     hnbuf = ws + OFF_HN;
    _Float16*  stf   = (_Float16*)(ws + OFF_STF);
    unsigned*  bar   = (unsigned*)(ws + OFF_BAR);

    const int tid = threadIdx.x;
    const int bid = blockIdx.x;
    const int g   = bid & (GR_ - 1);     // bid%8 -> expected per-XCD group
    const int idx = bid >> 3;            // 0..59 within group
    const int l   = idx / NCG_;
    const int cgp = idx - l*NCG_;
    const int colbase = cgp * CPB_;

    unsigned* gbar = bar + g*GBAR_STRIDE;
    unsigned* cnt  = &gbar[0];
    unsigned* ep   = &gbar[32];
    unsigned* det  = &gbar[64];

    __shared__ _Float16 w_lds[CPB_][WSTR];     // 62208 B
    __shared__ float    nrm_lds[2][KIP0];      //  1792 B
    __shared__ int      mode_sh;

    load_weights(l, colbase, tid, wih0, wihr, whh, rmean, rvar, w_lds, nrm_lds);

    // ---- XCD placement detection (one-time) ----
    unsigned myxcd;
    asm volatile("s_getreg_b32 %0, hwreg(HW_REG_XCC_ID)" : "=s"(myxcd));
    if (tid == 0)
        __hip_atomic_store(&det[idx], myxcd + 1u, __ATOMIC_RELEASE,
                           __HIP_MEMORY_SCOPE_AGENT);
    group_barrier(cnt, ep, tid, 1u, false);    // safe barrier (any placement)
    if (tid == 0) {
        int uni = 1;
        for (int i = 0; i < SPG_; ++i) {
            unsigned v = __hip_atomic_load(&det[i], __ATOMIC_RELAXED,
                                           __HIP_MEMORY_SCOPE_AGENT);
            if (v != myxcd + 1u) uni = 0;
        }
        mode_sh = uni;
    }
    __syncthreads();
    const bool fast = (mode_sh != 0);   // uniform predicate -> all blocks agree

    const int wid  = tid >> 6;
    const int lane = tid & 63;

    for (int tau = 0; tau < T_ + L_ - 1; ++tau) {
        const int t = tau - l;
        if (t >= 0 && t < T_)
            phase1_dispatch(g, l, t, colbase, tid, x, stf, bih, bhh,
                            zbuf, hnbuf, w_lds, nrm_lds);
        group_barrier(cnt, ep, tid, (unsigned)(2*tau + 2), fast);
        phase2_work(g, tau, idx*4 + wid, lane, lng, lnb, state, stf, zbuf, hnbuf, out);
        group_barrier(cnt, ep, tid, (unsigned)(2*tau + 3), fast);
    }
}

// ======================= non-cooperative fallback path =======================
__launch_bounds__(NTHR)
__global__ void k_p1(const float* __restrict__ x,
                     const float* __restrict__ rmean, const float* __restrict__ rvar,
                     const float* __restrict__ wih0,  const float* __restrict__ wihr,
                     const float* __restrict__ whh,   const float* __restrict__ bih,
                     const float* __restrict__ bhh,   float* __restrict__ ws, int tau)
{
    const int tid = threadIdx.x;
    const int bid = blockIdx.x;
    const int g   = bid & (GR_ - 1);
    const int idx = bid >> 3;
    const int l   = idx / NCG_;
    const int cgp = idx - l*NCG_;
    const int colbase = cgp * CPB_;
    const int t = tau - l;
    if (t < 0 || t >= T_) return;

    float*    zbuf  = ws + OFF_Z;
    float*    hnbuf = ws + OFF_HN;
    _Float16* stf   = (_Float16*)(ws + OFF_STF);

    __shared__ _Float16 w_lds[CPB_][WSTR];
    __shared__ float    nrm_lds[2][KIP0];
    load_weights(l, colbase, tid, wih0, wihr, whh, rmean, rvar, w_lds, nrm_lds);
    phase1_dispatch(g, l, t, colbase, tid, x, stf, bih, bhh, zbuf, hnbuf, w_lds, nrm_lds);
}

__launch_bounds__(NTHR)
__global__ void k_p2(const float* __restrict__ lng, const float* __restrict__ lnb,
                     float* __restrict__ ws, float* __restrict__ out, int tau)
{
    float*    state = ws + OFF_STATE;
    float*    zbuf  = ws + OFF_Z;
    float*    hnbuf = ws + OFF_HN;
    _Float16* stf   = (_Float16*)(ws + OFF_STF);
    const int bid = blockIdx.x;
    const int g   = bid & (GR_ - 1);
    const int idx = bid >> 3;
    phase2_work(g, tau, idx*4 + (threadIdx.x >> 6), threadIdx.x & 63,
                lng, lnb, state, stf, zbuf, hnbuf, out);
}

extern "C" void kernel_launch(void* const* d_in, const int* in_sizes, int n_in,
                              void* d_out, int out_size, void* d_ws, size_t ws_size,
                              hipStream_t stream) {
    (void)in_sizes; (void)n_in; (void)out_size; (void)ws_size;
    const float* x     = (const float*)d_in[0];
    const float* h0    = (const float*)d_in[1];
    const float* rmean = (const float*)d_in[2];
    const float* rvar  = (const float*)d_in[3];
    const float* wih0  = (const float*)d_in[4];
    const float* wihr  = (const float*)d_in[5];
    const float* whh   = (const float*)d_in[6];
    const float* bih   = (const float*)d_in[7];
    const float* bhh   = (const float*)d_in[8];
    const float* lng   = (const float*)d_in[9];
    const float* lnb   = (const float*)d_in[10];
    float* out = (float*)d_out;
    float* ws  = (float*)d_ws;

    k_init<<<dim3(240), dim3(NTHR), 0, stream>>>(h0, ws);

    int ncu = 0, nb = 0;
    hipDeviceGetAttribute(&ncu, hipDeviceAttributeMultiprocessorCount, 0);
    hipError_t qerr = hipOccupancyMaxActiveBlocksPerMultiprocessor(
        &nb, (const void*)gru_coop_kernel, NTHR, 0);
    const bool coop_ok = (qerr == hipSuccess) && (nb > 0) &&
                         ((long long)nb * (long long)ncu >= NBLK);

    if (coop_ok) {
        void* args[13] = {
            (void*)&x, (void*)&h0, (void*)&rmean, (void*)&rvar,
            (void*)&wih0, (void*)&wihr, (void*)&whh,
            (void*)&bih, (void*)&bhh, (void*)&lng, (void*)&lnb,
            (void*)&out, (void*)&ws
        };
        hipLaunchCooperativeKernel((void*)gru_coop_kernel,
                                   dim3(NBLK), dim3(NTHR), args, 0, stream);
    } else {
        for (int tau = 0; tau < T_ + L_ - 1; ++tau) {
            k_p1<<<dim3(NBLK), dim3(NTHR), 0, stream>>>(
                x, rmean, rvar, wih0, wihr, whh, bih, bhh, ws, tau);
            k_p2<<<dim3(NBLK), dim3(NTHR), 0, stream>>>(lng, lnb, ws, out, tau);
        }
    }
}